// Round 10
// baseline (9249.532 us; speedup 1.0000x reference)
//
#include <hip/hip_runtime.h>
#include <math.h>

#define B_   8
#define S_   1024
#define FIN  32
#define D_   512
#define H_   8
#define L_   6
#define DFF_ 2048
#define DK_  64

// non-contracted f32 ops (separate mul + add, no FMA) — attention einsum semantics
__device__ __forceinline__ float mulrn(float a, float b) { return __fmul_rn(a, b); }
__device__ __forceinline__ float addrn(float a, float b) { return __fadd_rn(a, b); }

// ---------------- embed: h = (x @ emb_w + emb_b) + pe  [f32, sequential-k FMA] ----------------
__global__ __launch_bounds__(128) void k_embed(const float* __restrict__ x,
                                               const float* __restrict__ emb_w,
                                               const float* __restrict__ emb_b,
                                               const float* __restrict__ pe,
                                               float* __restrict__ h) {
    int row = blockIdx.x;            // b*S + s
    int s = row & (S_ - 1);
    int t = threadIdx.x;             // 128 threads, 4 cols each
    __shared__ float xs[FIN];
    if (t < FIN) xs[t] = x[row * FIN + t];
    __syncthreads();
    int d = t * 4;
    float a0 = 0.f, a1 = 0.f, a2 = 0.f, a3 = 0.f;
#pragma unroll
    for (int k = 0; k < FIN; ++k) {          // strict k-ascending single-chain FMA
        float xv = xs[k];
        const float* wr = &emb_w[k * D_ + d];
        a0 = fmaf(xv, wr[0], a0);
        a1 = fmaf(xv, wr[1], a1);
        a2 = fmaf(xv, wr[2], a2);
        a3 = fmaf(xv, wr[3], a3);
    }
    const float* bb = &emb_b[d];
    const float* pp = &pe[s * D_ + d];
    float4 o;
    o.x = addrn(addrn(a0, bb[0]), pp[0]);
    o.y = addrn(addrn(a1, bb[1]), pp[1]);
    o.z = addrn(addrn(a2, bb[2]), pp[2]);
    o.w = addrn(addrn(a3, bb[3]), pp[3]);
    *(float4*)&h[(size_t)row * D_ + d] = o;
}

// ---------------- tiled f32 GEMM: C = A[M,K] @ W[K,N] + bias ----------------
// 64x128 tile, BK=16, 256 threads, 4x8/thread: 32 FMA per 3 b128 LDS reads (VALU-dominant).
// Reg-prefetch + LDS double-buffer, one barrier per panel. Per-element strict k-ascending
// single-accumulator FMA chain — bit-identical to rounds 6-9.
template<bool RELU>
__global__ __launch_bounds__(256) void k_gemm(const float* __restrict__ A,
                                              const float* __restrict__ W,
                                              const float* __restrict__ bias,
                                              float* __restrict__ C,
                                              int M, int N, int K) {
    __shared__ float As[2][16][68];    // [buf][k][m]
    __shared__ float Bs[2][16][132];   // [buf][k][n]
    int bm = blockIdx.y * 64, bn = blockIdx.x * 128;
    int t = threadIdx.x;
    int tr = t >> 4, tc = t & 15;          // compute map: rows tr*4.., cols tc*8..
    int ar = t >> 2, ak = (t & 3) * 4;     // A load map (256 f4 = 64r x 4 f4)
    int wk = t >> 5, wn = (t & 31) * 4;    // W load map (512 f4 = 16k x 32 f4; 2/thread)
    float acc[4][8] = {};

    // preload panel 0 into buf 0
    float4 pa  = *(const float4*)&A[(size_t)(bm + ar) * K + ak];
    float4 pw0 = *(const float4*)&W[(size_t)wk * N + bn + wn];
    float4 pw1 = *(const float4*)&W[(size_t)(wk + 8) * N + bn + wn];
    As[0][ak + 0][ar] = pa.x; As[0][ak + 1][ar] = pa.y;
    As[0][ak + 2][ar] = pa.z; As[0][ak + 3][ar] = pa.w;
    *(float4*)&Bs[0][wk][wn]     = pw0;
    *(float4*)&Bs[0][wk + 8][wn] = pw1;
    __syncthreads();

    const int nP = K >> 4;
    for (int p = 0; p < nP; ++p) {
        int cur = p & 1;
        if (p + 1 < nP) {                  // issue next panel's global loads early
            pa  = *(const float4*)&A[(size_t)(bm + ar) * K + (p + 1) * 16 + ak];
            pw0 = *(const float4*)&W[(size_t)((p + 1) * 16 + wk) * N + bn + wn];
            pw1 = *(const float4*)&W[(size_t)((p + 1) * 16 + wk + 8) * N + bn + wn];
        }
#pragma unroll
        for (int kk = 0; kk < 16; ++kk) {  // ascending within panel
            float4 av = *(const float4*)&As[cur][kk][tr * 4];
            float4 b0 = *(const float4*)&Bs[cur][kk][tc * 8];
            float4 b1 = *(const float4*)&Bs[cur][kk][tc * 8 + 4];
            acc[0][0] = fmaf(av.x, b0.x, acc[0][0]); acc[0][1] = fmaf(av.x, b0.y, acc[0][1]);
            acc[0][2] = fmaf(av.x, b0.z, acc[0][2]); acc[0][3] = fmaf(av.x, b0.w, acc[0][3]);
            acc[0][4] = fmaf(av.x, b1.x, acc[0][4]); acc[0][5] = fmaf(av.x, b1.y, acc[0][5]);
            acc[0][6] = fmaf(av.x, b1.z, acc[0][6]); acc[0][7] = fmaf(av.x, b1.w, acc[0][7]);
            acc[1][0] = fmaf(av.y, b0.x, acc[1][0]); acc[1][1] = fmaf(av.y, b0.y, acc[1][1]);
            acc[1][2] = fmaf(av.y, b0.z, acc[1][2]); acc[1][3] = fmaf(av.y, b0.w, acc[1][3]);
            acc[1][4] = fmaf(av.y, b1.x, acc[1][4]); acc[1][5] = fmaf(av.y, b1.y, acc[1][5]);
            acc[1][6] = fmaf(av.y, b1.z, acc[1][6]); acc[1][7] = fmaf(av.y, b1.w, acc[1][7]);
            acc[2][0] = fmaf(av.z, b0.x, acc[2][0]); acc[2][1] = fmaf(av.z, b0.y, acc[2][1]);
            acc[2][2] = fmaf(av.z, b0.z, acc[2][2]); acc[2][3] = fmaf(av.z, b0.w, acc[2][3]);
            acc[2][4] = fmaf(av.z, b1.x, acc[2][4]); acc[2][5] = fmaf(av.z, b1.y, acc[2][5]);
            acc[2][6] = fmaf(av.z, b1.z, acc[2][6]); acc[2][7] = fmaf(av.z, b1.w, acc[2][7]);
            acc[3][0] = fmaf(av.w, b0.x, acc[3][0]); acc[3][1] = fmaf(av.w, b0.y, acc[3][1]);
            acc[3][2] = fmaf(av.w, b0.z, acc[3][2]); acc[3][3] = fmaf(av.w, b0.w, acc[3][3]);
            acc[3][4] = fmaf(av.w, b1.x, acc[3][4]); acc[3][5] = fmaf(av.w, b1.y, acc[3][5]);
            acc[3][6] = fmaf(av.w, b1.z, acc[3][6]); acc[3][7] = fmaf(av.w, b1.w, acc[3][7]);
        }
        if (p + 1 < nP) {                  // write next panel to other buffer
            int nxt = cur ^ 1;
            As[nxt][ak + 0][ar] = pa.x; As[nxt][ak + 1][ar] = pa.y;
            As[nxt][ak + 2][ar] = pa.z; As[nxt][ak + 3][ar] = pa.w;
            *(float4*)&Bs[nxt][wk][wn]     = pw0;
            *(float4*)&Bs[nxt][wk + 8][wn] = pw1;
        }
        __syncthreads();                   // one barrier per panel
    }
    float4 ba = *(const float4*)&bias[bn + tc * 8];
    float4 bb = *(const float4*)&bias[bn + tc * 8 + 4];
#pragma unroll
    for (int i = 0; i < 4; ++i) {
        float4 o0, o1;
        o0.x = addrn(acc[i][0], ba.x); o0.y = addrn(acc[i][1], ba.y);
        o0.z = addrn(acc[i][2], ba.z); o0.w = addrn(acc[i][3], ba.w);
        o1.x = addrn(acc[i][4], bb.x); o1.y = addrn(acc[i][5], bb.y);
        o1.z = addrn(acc[i][6], bb.z); o1.w = addrn(acc[i][7], bb.w);
        if (RELU) {
            o0.x = fmaxf(o0.x, 0.f); o0.y = fmaxf(o0.y, 0.f);
            o0.z = fmaxf(o0.z, 0.f); o0.w = fmaxf(o0.w, 0.f);
            o1.x = fmaxf(o1.x, 0.f); o1.y = fmaxf(o1.y, 0.f);
            o1.z = fmaxf(o1.z, 0.f); o1.w = fmaxf(o1.w, 0.f);
        }
        *(float4*)&C[(size_t)(bm + tr * 4 + i) * N + bn + tc * 8]     = o0;
        *(float4*)&C[(size_t)(bm + tr * 4 + i) * N + bn + tc * 8 + 4] = o1;
    }
}

// ---------------- attention, numpy-faithful f32 ----------------
// grid (H, S/16, B); block 256 = 16 rows x 16 lanes. Arithmetic identical to rounds 5-9:
// scores strict d-ascending non-FMA; softmax per-lane contiguous 64-slice j-ascending +
// xor{1,2,4,8} tree; p/denom via __fdiv_rn; PV strict j-ascending non-FMA.
// This round: transposed-padded score layout Ss[j_in_slice][slice][row] — phases B/C/D use
// compile-time immediate LDS offsets (zero per-element address VALU); B/C 2-way conflicts
// (free), D reads broadcast. Same elements, same traversal order.
__global__ __launch_bounds__(256) void k_attn(const float* q,
                                              const float* __restrict__ kg,
                                              const float* __restrict__ vg,
                                              float* ctx) {
    __shared__ float KVs[32][68];       // K tiles, then V tiles (time-shared)
    __shared__ float Ss[64][16][17];    // [j_in_slice][slice][row(pad)]
    int hh = blockIdx.x;
    int ch = blockIdx.y;
    int b  = blockIdx.z;
    int t  = threadIdx.x;
    int r  = t >> 4, c16 = t & 15;
    const int row0 = ch * 16;
    const size_t base = (size_t)b * S_ * D_ + hh * DK_;
    const int srr = t >> 4, scc = (t & 15) * 4;   // staging coords

    // ---- stage Q chunk via LDS, hoist own row to registers ----
    *(float4*)&KVs[srr][scc] = *(const float4*)&q[base + (size_t)(row0 + srr) * D_ + scc];
    __syncthreads();
    float4 qr[16];
#pragma unroll
    for (int i = 0; i < 16; ++i) qr[i] = *(float4*)&KVs[r][i * 4];

    // ---- phase A: scores; 32 tiles x 32 keys; thread computes keys {c16, c16+16} ----
    float4 nx0 = *(const float4*)&kg[base + (size_t)srr * D_ + scc];
    float4 nx1 = *(const float4*)&kg[base + (size_t)(srr + 16) * D_ + scc];
    __syncthreads();            // qr reads done before KVs overwrite
    *(float4*)&KVs[srr][scc] = nx0;
    *(float4*)&KVs[srr + 16][scc] = nx1;
    __syncthreads();
    for (int kt = 0; kt < 32; ++kt) {
        if (kt < 31) {          // issue next tile's loads early (regs; no LDS hazard)
            size_t rowb = base + (size_t)((kt + 1) * 32) * D_;
            nx0 = *(const float4*)&kg[rowb + (size_t)srr * D_ + scc];
            nx1 = *(const float4*)&kg[rowb + (size_t)(srr + 16) * D_ + scc];
        }
        float s0 = 0.f, s1 = 0.f;
#pragma unroll
        for (int d4 = 0; d4 < 16; ++d4) {      // strict d-ascending, no FMA (x,y,z,w order)
            float4 qv = qr[d4];
            float4 k0 = *(float4*)&KVs[c16][d4 * 4];
            float4 k1 = *(float4*)&KVs[c16 + 16][d4 * 4];
            s0 = addrn(s0, mulrn(qv.x, k0.x)); s1 = addrn(s1, mulrn(qv.x, k1.x));
            s0 = addrn(s0, mulrn(qv.y, k0.y)); s1 = addrn(s1, mulrn(qv.y, k1.y));
            s0 = addrn(s0, mulrn(qv.z, k0.z)); s1 = addrn(s1, mulrn(qv.z, k1.z));
            s0 = addrn(s0, mulrn(qv.w, k0.w)); s1 = addrn(s1, mulrn(qv.w, k1.w));
        }
        int jg0 = kt * 32 + c16;
        int jg1 = jg0 + 16;
        Ss[jg0 & 63][jg0 >> 6][r] = mulrn(s0, 0.125f);    // / sqrt(64)
        Ss[jg1 & 63][jg1 >> 6][r] = mulrn(s1, 0.125f);
        __syncthreads();        // current-tile reads done
        if (kt < 31) {
            *(float4*)&KVs[srr][scc] = nx0;
            *(float4*)&KVs[srr + 16][scc] = nx1;
            __syncthreads();
        }
    }

    // ---- phase B: exact row max (lane's contiguous 64-slice j-ascending + xor tree) ----
    float mx = -INFINITY;
#pragma unroll
    for (int jj = 0; jj < 64; ++jj)            // key j = c16*64 + jj, ascending
        mx = fmaxf(mx, Ss[jj][c16][r]);
    mx = fmaxf(mx, __shfl_xor(mx, 1));
    mx = fmaxf(mx, __shfl_xor(mx, 2));
    mx = fmaxf(mx, __shfl_xor(mx, 4));
    mx = fmaxf(mx, __shfl_xor(mx, 8));

    // ---- phase C: p = exp(s - m); denom; attn = p / denom ----
    float psum = 0.f;
#pragma unroll
    for (int jj = 0; jj < 64; ++jj) {
        float p = expf(__fsub_rn(Ss[jj][c16][r], mx));
        Ss[jj][c16][r] = p;
        psum = addrn(psum, p);
    }
    psum = addrn(psum, __shfl_xor(psum, 1));
    psum = addrn(psum, __shfl_xor(psum, 2));
    psum = addrn(psum, __shfl_xor(psum, 4));
    psum = addrn(psum, __shfl_xor(psum, 8));
#pragma unroll
    for (int jj = 0; jj < 64; ++jj)
        Ss[jj][c16][r] = __fdiv_rn(Ss[jj][c16][r], psum);

    // ---- phase D: ctx[r][d] = sum_j attn[r][j]*v[j][d], strict j-ascending, no FMA ----
    int d0 = c16 * 4;
    float a0 = 0.f, a1 = 0.f, a2 = 0.f, a3 = 0.f;
    nx0 = *(const float4*)&vg[base + (size_t)srr * D_ + scc];
    nx1 = *(const float4*)&vg[base + (size_t)(srr + 16) * D_ + scc];
    __syncthreads();            // phase-C writes visible; staging guard
    *(float4*)&KVs[srr][scc] = nx0;
    *(float4*)&KVs[srr + 16][scc] = nx1;
    __syncthreads();
    for (int vt = 0; vt < 32; ++vt) {
        if (vt < 31) {
            size_t rowb = base + (size_t)((vt + 1) * 32) * D_;
            nx0 = *(const float4*)&vg[rowb + (size_t)srr * D_ + scc];
            nx1 = *(const float4*)&vg[rowb + (size_t)(srr + 16) * D_ + scc];
        }
        // p for key j = vt*32 + jl lives at Ss[(vt&1)*32 + jl][vt>>1][r]:
        // base dynamic per vt, offset jl*272 floats = compile-time immediate per unrolled jl
        const float* srow = &Ss[(vt & 1) * 32][vt >> 1][r];
#pragma unroll
        for (int jl = 0; jl < 32; ++jl) {      // j ascending
            float p = srow[jl * 272];
            float4 v4 = *(float4*)&KVs[jl][d0];
            a0 = addrn(a0, mulrn(p, v4.x));
            a1 = addrn(a1, mulrn(p, v4.y));
            a2 = addrn(a2, mulrn(p, v4.z));
            a3 = addrn(a3, mulrn(p, v4.w));
        }
        __syncthreads();
        if (vt < 31) {
            *(float4*)&KVs[srr][scc] = nx0;
            *(float4*)&KVs[srr + 16][scc] = nx1;
            __syncthreads();
        }
    }
    float4 o = {a0, a1, a2, a3};
    *(float4*)&ctx[base + (size_t)(row0 + r) * D_ + d0] = o;
}

// ---------------- h = LN(h + res), f32 two-pass ----------------
__global__ __launch_bounds__(256) void k_add_ln(float* h,
                                                const float* __restrict__ res,
                                                const float* __restrict__ g,
                                                const float* __restrict__ bta) {
    int row = blockIdx.x;
    int t = threadIdx.x;
    size_t base = (size_t)row * D_;
    float y0 = addrn(h[base + t],       res[base + t]);
    float y1 = addrn(h[base + t + 256], res[base + t + 256]);
    __shared__ float red[4];
    int w = t >> 6;
    float s = y0 + y1;
#pragma unroll
    for (int o = 1; o < 64; o <<= 1) s += __shfl_xor(s, o);
    if ((t & 63) == 0) red[w] = s;
    __syncthreads();
    float mean = (red[0] + red[1] + red[2] + red[3]) * (1.f / D_);
    __syncthreads();
    float d0 = __fsub_rn(y0, mean), d1 = __fsub_rn(y1, mean);
    s = mulrn(d0, d0) + mulrn(d1, d1);
#pragma unroll
    for (int o = 1; o < 64; o <<= 1) s += __shfl_xor(s, o);
    if ((t & 63) == 0) red[w] = s;
    __syncthreads();
    float var = (red[0] + red[1] + red[2] + red[3]) * (1.f / D_);
    float rstd = __fdiv_rn(1.0f, sqrtf(__fadd_rn(var, 1e-5f)));
    h[base + t]       = addrn(mulrn(mulrn(d0, rstd), g[t]),       bta[t]);
    h[base + t + 256] = addrn(mulrn(mulrn(d1, rstd), g[t + 256]), bta[t + 256]);
}

// ---------------- pooled = mean over S (f32) ----------------
__global__ __launch_bounds__(256) void k_pool(const float* __restrict__ h,
                                              float* __restrict__ pooled) {
    int blk = blockIdx.x;           // B*8
    int b = blk >> 3, dc = (blk & 7) * 64;
    int t = threadIdx.x;
    int d = dc + (t & 63), sg = t >> 6;
    float s = 0.f;
    for (int ss = sg; ss < S_; ss += 4)
        s = addrn(s, h[((size_t)b * S_ + ss) * D_ + d]);
    __shared__ float sh[4][64];
    sh[sg][t & 63] = s;
    __syncthreads();
    if (t < 64)
        pooled[b * D_ + dc + t] = (sh[0][t] + sh[1][t] + sh[2][t] + sh[3][t]) * (1.f / S_);
}

// ---------------- head MLP (single block, f32, sequential-k FMA) ----------------
__global__ __launch_bounds__(256) void k_head(const float* __restrict__ pooled,
                                              const float* __restrict__ w1, const float* __restrict__ b1,
                                              const float* __restrict__ w2, const float* __restrict__ b2,
                                              const float* __restrict__ w3, const float* __restrict__ b3,
                                              float* __restrict__ out) {
    __shared__ float ps[B_][D_];
    __shared__ float z1[B_][256];
    __shared__ float z2[B_][128];
    int t = threadIdx.x;
    for (int i = t; i < B_ * D_; i += 256) ps[i >> 9][i & 511] = pooled[i];
    __syncthreads();
    {
        float acc[B_] = {};
        for (int k = 0; k < D_; ++k) {
            float w = w1[k * 256 + t];
#pragma unroll
            for (int b = 0; b < B_; ++b) acc[b] = fmaf(ps[b][k], w, acc[b]);
        }
#pragma unroll
        for (int b = 0; b < B_; ++b) z1[b][t] = fmaxf(addrn(acc[b], b1[t]), 0.f);
    }
    __syncthreads();
    if (t < 128) {
        float acc[B_] = {};
        for (int k = 0; k < 256; ++k) {
            float w = w2[k * 128 + t];
#pragma unroll
            for (int b = 0; b < B_; ++b) acc[b] = fmaf(z1[b][k], w, acc[b]);
        }
#pragma unroll
        for (int b = 0; b < B_; ++b) z2[b][t] = fmaxf(addrn(acc[b], b2[t]), 0.f);
    }
    __syncthreads();
    if (t < B_ * 3) {
        int b = t / 3, c = t % 3;
        float acc = 0.f;
        for (int k = 0; k < 128; ++k) acc = fmaf(z2[b][k], w3[k * 3 + c], acc);
        out[t] = addrn(acc, b3[c]);
    }
}

extern "C" void kernel_launch(void* const* d_in, const int* in_sizes, int n_in,
                              void* d_out, int out_size, void* d_ws, size_t ws_size,
                              hipStream_t stream) {
    const float* x     = (const float*)d_in[0];
    const float* pe    = (const float*)d_in[1];
    const float* emb_w = (const float*)d_in[2];
    const float* emb_b = (const float*)d_in[3];
    const float* Wq    = (const float*)d_in[4];
    const float* bq    = (const float*)d_in[5];
    const float* Wk    = (const float*)d_in[6];
    const float* bk    = (const float*)d_in[7];
    const float* Wv    = (const float*)d_in[8];
    const float* bv    = (const float*)d_in[9];
    const float* Wo    = (const float*)d_in[10];
    const float* bo    = (const float*)d_in[11];
    const float* ln1_g = (const float*)d_in[12];
    const float* ln1_b = (const float*)d_in[13];
    const float* ln2_g = (const float*)d_in[14];
    const float* ln2_b = (const float*)d_in[15];
    const float* W1    = (const float*)d_in[16];
    const float* b1    = (const float*)d_in[17];
    const float* W2    = (const float*)d_in[18];
    const float* b2    = (const float*)d_in[19];
    const float* fc1_w = (const float*)d_in[20];
    const float* fc1_b = (const float*)d_in[21];
    const float* fc2_w = (const float*)d_in[22];
    const float* fc2_b = (const float*)d_in[23];
    const float* fc3_w = (const float*)d_in[24];
    const float* fc3_b = (const float*)d_in[25];

    const size_t NBS = (size_t)B_ * S_ * D_;   // 4,194,304 floats
    float* ws = (float*)d_ws;
    const int MROWS = B_ * S_;                 // 8192

    // layout (f32, 67.1 MB): h | q | k | v | pooled  (ctx->q, Wo-out->k, W2-out->v, ff1 over q+k)
    float* h = ws;
    float* q = h + NBS;
    float* k = q + NBS;
    float* v = k + NBS;
    float* pooled = v + NBS;

    k_embed<<<MROWS, 128, 0, stream>>>(x, emb_w, emb_b, pe, h);

    dim3 g512(D_ / 128, MROWS / 64);       // (4,128)  QKVO: 512 blocks
    dim3 gff(DFF_ / 128, 4096 / 64);       // (16,64)  W1: 1024 blocks per 4096-row chunk
    dim3 gw2(D_ / 128, 4096 / 64);         // (4,64)   W2: 256 blocks
    dim3 gattn(H_, S_ / 16, B_);           // (8,64,8)

    for (int l = 0; l < L_; ++l) {
        const float* wq = Wq + (size_t)l * D_ * D_;
        const float* wk = Wk + (size_t)l * D_ * D_;
        const float* wv = Wv + (size_t)l * D_ * D_;
        const float* wo = Wo + (size_t)l * D_ * D_;
        k_gemm<false><<<g512, 256, 0, stream>>>(h, wq, bq + l * D_, q, MROWS, D_, D_);
        k_gemm<false><<<g512, 256, 0, stream>>>(h, wk, bk + l * D_, k, MROWS, D_, D_);
        k_gemm<false><<<g512, 256, 0, stream>>>(h, wv, bv + l * D_, v, MROWS, D_, D_);
        k_attn<<<gattn, 256, 0, stream>>>(q, k, v, q);                 // ctx in place
        k_gemm<false><<<g512, 256, 0, stream>>>(q, wo, bo + l * D_, k, MROWS, D_, D_);
        k_add_ln<<<MROWS, 256, 0, stream>>>(h, k, ln1_g + l * D_, ln1_b + l * D_);
        for (int c = 0; c < 2; ++c) {
            float* ff1 = q;                                            // 4096x2048 over dead q+k
            k_gemm<true ><<<gff, 256, 0, stream>>>(h + (size_t)c * 4096 * D_,
                W1 + (size_t)l * D_ * DFF_, b1 + l * DFF_, ff1, 4096, DFF_, D_);
            k_gemm<false><<<gw2, 256, 0, stream>>>(ff1,
                W2 + (size_t)l * DFF_ * D_, b2 + l * D_, v + (size_t)c * 4096 * D_, 4096, D_, DFF_);
        }
        k_add_ln<<<MROWS, 256, 0, stream>>>(h, v, ln2_g + l * D_, ln2_b + l * D_);
    }

    k_pool<<<B_ * 8, 256, 0, stream>>>(h, pooled);
    k_head<<<1, 256, 0, stream>>>(pooled, fc1_w, fc1_b, fc2_w, fc2_b, fc3_w, fc3_b, (float*)d_out);
}

// Round 11
// 7308.824 us; speedup vs baseline: 1.2655x; 1.2655x over previous
//
#include <hip/hip_runtime.h>
#include <math.h>

#define B_   8
#define S_   1024
#define FIN  32
#define D_   512
#define H_   8
#define L_   6
#define DFF_ 2048
#define DK_  64

// non-contracted f32 ops (separate mul + add, no FMA) — attention einsum semantics
__device__ __forceinline__ float mulrn(float a, float b) { return __fmul_rn(a, b); }
__device__ __forceinline__ float addrn(float a, float b) { return __fadd_rn(a, b); }

// ---------------- embed: h = (x @ emb_w + emb_b) + pe  [f32, sequential-k FMA] ----------------
__global__ __launch_bounds__(128) void k_embed(const float* __restrict__ x,
                                               const float* __restrict__ emb_w,
                                               const float* __restrict__ emb_b,
                                               const float* __restrict__ pe,
                                               float* __restrict__ h) {
    int row = blockIdx.x;            // b*S + s
    int s = row & (S_ - 1);
    int t = threadIdx.x;             // 128 threads, 4 cols each
    __shared__ float xs[FIN];
    if (t < FIN) xs[t] = x[row * FIN + t];
    __syncthreads();
    int d = t * 4;
    float a0 = 0.f, a1 = 0.f, a2 = 0.f, a3 = 0.f;
#pragma unroll
    for (int k = 0; k < FIN; ++k) {          // strict k-ascending single-chain FMA
        float xv = xs[k];
        const float* wr = &emb_w[k * D_ + d];
        a0 = fmaf(xv, wr[0], a0);
        a1 = fmaf(xv, wr[1], a1);
        a2 = fmaf(xv, wr[2], a2);
        a3 = fmaf(xv, wr[3], a3);
    }
    const float* bb = &emb_b[d];
    const float* pp = &pe[s * D_ + d];
    float4 o;
    o.x = addrn(addrn(a0, bb[0]), pp[0]);
    o.y = addrn(addrn(a1, bb[1]), pp[1]);
    o.z = addrn(addrn(a2, bb[2]), pp[2]);
    o.w = addrn(addrn(a3, bb[3]), pp[3]);
    *(float4*)&h[(size_t)row * D_ + d] = o;
}

// ---------------- tiled f32 GEMM: C = A[M,K] @ W[K,N] + bias (round-9, best) ----------------
// 64x64 tile, BK=16, 256 threads, 4x4/thread, reg-prefetch + LDS double-buffer (one barrier
// per panel). Per-element strict k-ascending single-accumulator FMA chain.
template<bool RELU>
__global__ __launch_bounds__(256) void k_gemm(const float* __restrict__ A,
                                              const float* __restrict__ W,
                                              const float* __restrict__ bias,
                                              float* __restrict__ C,
                                              int M, int N, int K) {
    __shared__ float As[2][16][68];   // [buf][k][m]
    __shared__ float Bs[2][16][68];   // [buf][k][n]
    int bm = blockIdx.y * 64, bn = blockIdx.x * 64;
    int t = threadIdx.x;
    int tr = t >> 4, tc = t & 15;          // compute map
    int ar = t >> 2, ak = (t & 3) * 4;     // A load map
    int wk = t >> 4, wn = (t & 15) * 4;    // W load map
    float acc[4][4] = {};

    // preload panel 0 into buf 0
    float4 pa = *(const float4*)&A[(size_t)(bm + ar) * K + ak];
    float4 pw = *(const float4*)&W[(size_t)wk * N + bn + wn];
    As[0][ak + 0][ar] = pa.x; As[0][ak + 1][ar] = pa.y;
    As[0][ak + 2][ar] = pa.z; As[0][ak + 3][ar] = pa.w;
    *(float4*)&Bs[0][wk][wn] = pw;
    __syncthreads();

    const int nP = K >> 4;
    for (int p = 0; p < nP; ++p) {
        int cur = p & 1;
        if (p + 1 < nP) {                  // issue next panel's global loads early
            pa = *(const float4*)&A[(size_t)(bm + ar) * K + (p + 1) * 16 + ak];
            pw = *(const float4*)&W[(size_t)((p + 1) * 16 + wk) * N + bn + wn];
        }
#pragma unroll
        for (int kk = 0; kk < 16; ++kk) {  // ascending within panel
            float4 av = *(const float4*)&As[cur][kk][tr * 4];
            float4 bv = *(const float4*)&Bs[cur][kk][tc * 4];
            acc[0][0] = fmaf(av.x, bv.x, acc[0][0]); acc[0][1] = fmaf(av.x, bv.y, acc[0][1]);
            acc[0][2] = fmaf(av.x, bv.z, acc[0][2]); acc[0][3] = fmaf(av.x, bv.w, acc[0][3]);
            acc[1][0] = fmaf(av.y, bv.x, acc[1][0]); acc[1][1] = fmaf(av.y, bv.y, acc[1][1]);
            acc[1][2] = fmaf(av.y, bv.z, acc[1][2]); acc[1][3] = fmaf(av.y, bv.w, acc[1][3]);
            acc[2][0] = fmaf(av.z, bv.x, acc[2][0]); acc[2][1] = fmaf(av.z, bv.y, acc[2][1]);
            acc[2][2] = fmaf(av.z, bv.z, acc[2][2]); acc[2][3] = fmaf(av.z, bv.w, acc[2][3]);
            acc[3][0] = fmaf(av.w, bv.x, acc[3][0]); acc[3][1] = fmaf(av.w, bv.y, acc[3][1]);
            acc[3][2] = fmaf(av.w, bv.z, acc[3][2]); acc[3][3] = fmaf(av.w, bv.w, acc[3][3]);
        }
        if (p + 1 < nP) {                  // write next panel to other buffer
            int nxt = cur ^ 1;
            As[nxt][ak + 0][ar] = pa.x; As[nxt][ak + 1][ar] = pa.y;
            As[nxt][ak + 2][ar] = pa.z; As[nxt][ak + 3][ar] = pa.w;
            *(float4*)&Bs[nxt][wk][wn] = pw;
        }
        __syncthreads();                   // one barrier per panel
    }
    float4 b4 = *(const float4*)&bias[bn + tc * 4];
#pragma unroll
    for (int i = 0; i < 4; ++i) {
        float4 o;
        o.x = addrn(acc[i][0], b4.x); o.y = addrn(acc[i][1], b4.y);
        o.z = addrn(acc[i][2], b4.z); o.w = addrn(acc[i][3], b4.w);
        if (RELU) {
            o.x = fmaxf(o.x, 0.f); o.y = fmaxf(o.y, 0.f);
            o.z = fmaxf(o.z, 0.f); o.w = fmaxf(o.w, 0.f);
        }
        *(float4*)&C[(size_t)(bm + tr * 4 + i) * N + bn + tc * 4] = o;
    }
}

// ---------------- attention, numpy-faithful f32 ----------------
// grid (H, S/16, B); block 256 = 16 rows x 16 lanes. Arithmetic identical to rounds 5-10:
// scores strict d-ascending non-FMA; softmax per-lane contiguous 64-slice j-ascending +
// xor{1,2,4,8} tree; p/denom via __fdiv_rn; PV strict j-ascending non-FMA.
// Layout: transposed score array, flat with j-stride 276 (276%32=20 -> score writes ~2-way
// bank conflicts instead of 8-way at stride 272). Same elements, same traversal order.
__global__ __launch_bounds__(256) void k_attn(const float* q,
                                              const float* __restrict__ kg,
                                              const float* __restrict__ vg,
                                              float* ctx) {
    __shared__ float KVs[32][68];       // K tiles, then V tiles (time-shared)
    __shared__ float Ss[64 * 276];      // score(j, row r) at (j&63)*276 + (j>>6)*17 + r
    int hh = blockIdx.x;
    int ch = blockIdx.y;
    int b  = blockIdx.z;
    int t  = threadIdx.x;
    int r  = t >> 4, c16 = t & 15;
    const int row0 = ch * 16;
    const size_t base = (size_t)b * S_ * D_ + hh * DK_;
    const int srr = t >> 4, scc = (t & 15) * 4;   // staging coords

    // ---- stage Q chunk via LDS, hoist own row to registers ----
    *(float4*)&KVs[srr][scc] = *(const float4*)&q[base + (size_t)(row0 + srr) * D_ + scc];
    __syncthreads();
    float4 qr[16];
#pragma unroll
    for (int i = 0; i < 16; ++i) qr[i] = *(float4*)&KVs[r][i * 4];

    // ---- phase A: scores; 32 tiles x 32 keys; thread computes keys {c16, c16+16} ----
    float4 nx0 = *(const float4*)&kg[base + (size_t)srr * D_ + scc];
    float4 nx1 = *(const float4*)&kg[base + (size_t)(srr + 16) * D_ + scc];
    __syncthreads();            // qr reads done before KVs overwrite
    *(float4*)&KVs[srr][scc] = nx0;
    *(float4*)&KVs[srr + 16][scc] = nx1;
    __syncthreads();
    for (int kt = 0; kt < 32; ++kt) {
        if (kt < 31) {          // issue next tile's loads early (regs; no LDS hazard)
            size_t rowb = base + (size_t)((kt + 1) * 32) * D_;
            nx0 = *(const float4*)&kg[rowb + (size_t)srr * D_ + scc];
            nx1 = *(const float4*)&kg[rowb + (size_t)(srr + 16) * D_ + scc];
        }
        float s0 = 0.f, s1 = 0.f;
#pragma unroll
        for (int d4 = 0; d4 < 16; ++d4) {      // strict d-ascending, no FMA (x,y,z,w order)
            float4 qv = qr[d4];
            float4 k0 = *(float4*)&KVs[c16][d4 * 4];
            float4 k1 = *(float4*)&KVs[c16 + 16][d4 * 4];
            s0 = addrn(s0, mulrn(qv.x, k0.x)); s1 = addrn(s1, mulrn(qv.x, k1.x));
            s0 = addrn(s0, mulrn(qv.y, k0.y)); s1 = addrn(s1, mulrn(qv.y, k1.y));
            s0 = addrn(s0, mulrn(qv.z, k0.z)); s1 = addrn(s1, mulrn(qv.z, k1.z));
            s0 = addrn(s0, mulrn(qv.w, k0.w)); s1 = addrn(s1, mulrn(qv.w, k1.w));
        }
        int jg0 = kt * 32 + c16;
        int jg1 = jg0 + 16;
        Ss[(jg0 & 63) * 276 + (jg0 >> 6) * 17 + r] = mulrn(s0, 0.125f);   // / sqrt(64)
        Ss[(jg1 & 63) * 276 + (jg1 >> 6) * 17 + r] = mulrn(s1, 0.125f);
        __syncthreads();        // current-tile reads done
        if (kt < 31) {
            *(float4*)&KVs[srr][scc] = nx0;
            *(float4*)&KVs[srr + 16][scc] = nx1;
            __syncthreads();
        }
    }

    // ---- phase B: exact row max (lane's contiguous 64-slice j-ascending + xor tree) ----
    const int rbase = c16 * 17 + r;            // slice base for this lane's 64 keys
    float mx = -INFINITY;
#pragma unroll
    for (int jj = 0; jj < 64; ++jj)            // key j = c16*64 + jj, ascending
        mx = fmaxf(mx, Ss[jj * 276 + rbase]);
    mx = fmaxf(mx, __shfl_xor(mx, 1));
    mx = fmaxf(mx, __shfl_xor(mx, 2));
    mx = fmaxf(mx, __shfl_xor(mx, 4));
    mx = fmaxf(mx, __shfl_xor(mx, 8));

    // ---- phase C: p = exp(s - m); denom; attn = p / denom ----
    float psum = 0.f;
#pragma unroll
    for (int jj = 0; jj < 64; ++jj) {
        float p = expf(__fsub_rn(Ss[jj * 276 + rbase], mx));
        Ss[jj * 276 + rbase] = p;
        psum = addrn(psum, p);
    }
    psum = addrn(psum, __shfl_xor(psum, 1));
    psum = addrn(psum, __shfl_xor(psum, 2));
    psum = addrn(psum, __shfl_xor(psum, 4));
    psum = addrn(psum, __shfl_xor(psum, 8));
#pragma unroll
    for (int jj = 0; jj < 64; ++jj)
        Ss[jj * 276 + rbase] = __fdiv_rn(Ss[jj * 276 + rbase], psum);

    // ---- phase D: ctx[r][d] = sum_j attn[r][j]*v[j][d], strict j-ascending, no FMA ----
    int d0 = c16 * 4;
    float a0 = 0.f, a1 = 0.f, a2 = 0.f, a3 = 0.f;
    nx0 = *(const float4*)&vg[base + (size_t)srr * D_ + scc];
    nx1 = *(const float4*)&vg[base + (size_t)(srr + 16) * D_ + scc];
    __syncthreads();            // phase-C writes visible; staging guard
    *(float4*)&KVs[srr][scc] = nx0;
    *(float4*)&KVs[srr + 16][scc] = nx1;
    __syncthreads();
    for (int vt = 0; vt < 32; ++vt) {
        if (vt < 31) {
            size_t rowb = base + (size_t)((vt + 1) * 32) * D_;
            nx0 = *(const float4*)&vg[rowb + (size_t)srr * D_ + scc];
            nx1 = *(const float4*)&vg[rowb + (size_t)(srr + 16) * D_ + scc];
        }
        // p for key j = vt*32 + jl at Ss[((vt&1)*32 + jl)*276 + (vt>>1)*17 + r]
        const float* srow = &Ss[(vt & 1) * 32 * 276 + (vt >> 1) * 17 + r];
#pragma unroll
        for (int jl = 0; jl < 32; ++jl) {      // j ascending
            float p = srow[jl * 276];
            float4 v4 = *(float4*)&KVs[jl][d0];
            a0 = addrn(a0, mulrn(p, v4.x));
            a1 = addrn(a1, mulrn(p, v4.y));
            a2 = addrn(a2, mulrn(p, v4.z));
            a3 = addrn(a3, mulrn(p, v4.w));
        }
        __syncthreads();
        if (vt < 31) {
            *(float4*)&KVs[srr][scc] = nx0;
            *(float4*)&KVs[srr + 16][scc] = nx1;
            __syncthreads();
        }
    }
    float4 o = {a0, a1, a2, a3};
    *(float4*)&ctx[base + (size_t)(row0 + r) * D_ + d0] = o;
}

// ---------------- h = LN(h + res), f32 two-pass ----------------
__global__ __launch_bounds__(256) void k_add_ln(float* h,
                                                const float* __restrict__ res,
                                                const float* __restrict__ g,
                                                const float* __restrict__ bta) {
    int row = blockIdx.x;
    int t = threadIdx.x;
    size_t base = (size_t)row * D_;
    float y0 = addrn(h[base + t],       res[base + t]);
    float y1 = addrn(h[base + t + 256], res[base + t + 256]);
    __shared__ float red[4];
    int w = t >> 6;
    float s = y0 + y1;
#pragma unroll
    for (int o = 1; o < 64; o <<= 1) s += __shfl_xor(s, o);
    if ((t & 63) == 0) red[w] = s;
    __syncthreads();
    float mean = (red[0] + red[1] + red[2] + red[3]) * (1.f / D_);
    __syncthreads();
    float d0 = __fsub_rn(y0, mean), d1 = __fsub_rn(y1, mean);
    s = mulrn(d0, d0) + mulrn(d1, d1);
#pragma unroll
    for (int o = 1; o < 64; o <<= 1) s += __shfl_xor(s, o);
    if ((t & 63) == 0) red[w] = s;
    __syncthreads();
    float var = (red[0] + red[1] + red[2] + red[3]) * (1.f / D_);
    float rstd = __fdiv_rn(1.0f, sqrtf(__fadd_rn(var, 1e-5f)));
    h[base + t]       = addrn(mulrn(mulrn(d0, rstd), g[t]),       bta[t]);
    h[base + t + 256] = addrn(mulrn(mulrn(d1, rstd), g[t + 256]), bta[t + 256]);
}

// ---------------- pooled = mean over S (f32) ----------------
__global__ __launch_bounds__(256) void k_pool(const float* __restrict__ h,
                                              float* __restrict__ pooled) {
    int blk = blockIdx.x;           // B*8
    int b = blk >> 3, dc = (blk & 7) * 64;
    int t = threadIdx.x;
    int d = dc + (t & 63), sg = t >> 6;
    float s = 0.f;
    for (int ss = sg; ss < S_; ss += 4)
        s = addrn(s, h[((size_t)b * S_ + ss) * D_ + d]);
    __shared__ float sh[4][64];
    sh[sg][t & 63] = s;
    __syncthreads();
    if (t < 64)
        pooled[b * D_ + dc + t] = (sh[0][t] + sh[1][t] + sh[2][t] + sh[3][t]) * (1.f / S_);
}

// ---------------- head MLP (single block, f32, sequential-k FMA) ----------------
__global__ __launch_bounds__(256) void k_head(const float* __restrict__ pooled,
                                              const float* __restrict__ w1, const float* __restrict__ b1,
                                              const float* __restrict__ w2, const float* __restrict__ b2,
                                              const float* __restrict__ w3, const float* __restrict__ b3,
                                              float* __restrict__ out) {
    __shared__ float ps[B_][D_];
    __shared__ float z1[B_][256];
    __shared__ float z2[B_][128];
    int t = threadIdx.x;
    for (int i = t; i < B_ * D_; i += 256) ps[i >> 9][i & 511] = pooled[i];
    __syncthreads();
    {
        float acc[B_] = {};
        for (int k = 0; k < D_; ++k) {
            float w = w1[k * 256 + t];
#pragma unroll
            for (int b = 0; b < B_; ++b) acc[b] = fmaf(ps[b][k], w, acc[b]);
        }
#pragma unroll
        for (int b = 0; b < B_; ++b) z1[b][t] = fmaxf(addrn(acc[b], b1[t]), 0.f);
    }
    __syncthreads();
    if (t < 128) {
        float acc[B_] = {};
        for (int k = 0; k < 256; ++k) {
            float w = w2[k * 128 + t];
#pragma unroll
            for (int b = 0; b < B_; ++b) acc[b] = fmaf(z1[b][k], w, acc[b]);
        }
#pragma unroll
        for (int b = 0; b < B_; ++b) z2[b][t] = fmaxf(addrn(acc[b], b2[t]), 0.f);
    }
    __syncthreads();
    if (t < B_ * 3) {
        int b = t / 3, c = t % 3;
        float acc = 0.f;
        for (int k = 0; k < 128; ++k) acc = fmaf(z2[b][k], w3[k * 3 + c], acc);
        out[t] = addrn(acc, b3[c]);
    }
}

extern "C" void kernel_launch(void* const* d_in, const int* in_sizes, int n_in,
                              void* d_out, int out_size, void* d_ws, size_t ws_size,
                              hipStream_t stream) {
    const float* x     = (const float*)d_in[0];
    const float* pe    = (const float*)d_in[1];
    const float* emb_w = (const float*)d_in[2];
    const float* emb_b = (const float*)d_in[3];
    const float* Wq    = (const float*)d_in[4];
    const float* bq    = (const float*)d_in[5];
    const float* Wk    = (const float*)d_in[6];
    const float* bk    = (const float*)d_in[7];
    const float* Wv    = (const float*)d_in[8];
    const float* bv    = (const float*)d_in[9];
    const float* Wo    = (const float*)d_in[10];
    const float* bo    = (const float*)d_in[11];
    const float* ln1_g = (const float*)d_in[12];
    const float* ln1_b = (const float*)d_in[13];
    const float* ln2_g = (const float*)d_in[14];
    const float* ln2_b = (const float*)d_in[15];
    const float* W1    = (const float*)d_in[16];
    const float* b1    = (const float*)d_in[17];
    const float* W2    = (const float*)d_in[18];
    const float* b2    = (const float*)d_in[19];
    const float* fc1_w = (const float*)d_in[20];
    const float* fc1_b = (const float*)d_in[21];
    const float* fc2_w = (const float*)d_in[22];
    const float* fc2_b = (const float*)d_in[23];
    const float* fc3_w = (const float*)d_in[24];
    const float* fc3_b = (const float*)d_in[25];

    const size_t NBS = (size_t)B_ * S_ * D_;   // 4,194,304 floats
    float* ws = (float*)d_ws;
    const int MROWS = B_ * S_;                 // 8192

    // layout (f32, 67.1 MB): h | q | k | v | pooled  (ctx->q, Wo-out->k, W2-out->v, ff1 over q+k)
    float* h = ws;
    float* q = h + NBS;
    float* k = q + NBS;
    float* v = k + NBS;
    float* pooled = v + NBS;

    k_embed<<<MROWS, 128, 0, stream>>>(x, emb_w, emb_b, pe, h);

    dim3 g512(D_ / 64, MROWS / 64);        // (8,128)  QKVO: 1024 blocks, 4+ blocks/CU
    dim3 gff(DFF_ / 64, 4096 / 64);        // (32,64)  W1 per 4096-row chunk
    dim3 gw2(D_ / 64, 4096 / 64);          // (8,64)   W2
    dim3 gattn(H_, S_ / 16, B_);           // (8,64,8)

    for (int l = 0; l < L_; ++l) {
        const float* wq = Wq + (size_t)l * D_ * D_;
        const float* wk = Wk + (size_t)l * D_ * D_;
        const float* wv = Wv + (size_t)l * D_ * D_;
        const float* wo = Wo + (size_t)l * D_ * D_;
        k_gemm<false><<<g512, 256, 0, stream>>>(h, wq, bq + l * D_, q, MROWS, D_, D_);
        k_gemm<false><<<g512, 256, 0, stream>>>(h, wk, bk + l * D_, k, MROWS, D_, D_);
        k_gemm<false><<<g512, 256, 0, stream>>>(h, wv, bv + l * D_, v, MROWS, D_, D_);
        k_attn<<<gattn, 256, 0, stream>>>(q, k, v, q);                 // ctx in place
        k_gemm<false><<<g512, 256, 0, stream>>>(q, wo, bo + l * D_, k, MROWS, D_, D_);
        k_add_ln<<<MROWS, 256, 0, stream>>>(h, k, ln1_g + l * D_, ln1_b + l * D_);
        for (int c = 0; c < 2; ++c) {
            float* ff1 = q;                                            // 4096x2048 over dead q+k
            k_gemm<true ><<<gff, 256, 0, stream>>>(h + (size_t)c * 4096 * D_,
                W1 + (size_t)l * D_ * DFF_, b1 + l * DFF_, ff1, 4096, DFF_, D_);
            k_gemm<false><<<gw2, 256, 0, stream>>>(ff1,
                W2 + (size_t)l * DFF_ * D_, b2 + l * D_, v + (size_t)c * 4096 * D_, 4096, D_, DFF_);
        }
        k_add_ln<<<MROWS, 256, 0, stream>>>(h, v, ln2_g + l * D_, ln2_b + l * D_);
    }

    k_pool<<<B_ * 8, 256, 0, stream>>>(h, pooled);
    k_head<<<1, 256, 0, stream>>>(pooled, fc1_w, fc1_b, fc2_w, fc2_b, fc3_w, fc3_b, (float*)d_out);
}